// Round 3
// baseline (395.901 us; speedup 1.0000x reference)
//
#include <hip/hip_runtime.h>

// LSTM scan, B=8192 chains, T=2048 steps, D=H=2. 8 lanes/element.
// Round 10: dual-stream ILP. Exactly 1 wave/SIMD and in-order issue mean
// the per-step wall (203 cyc) = chain latency (~90-120) + UNFILLED stall
// (trans latency + DPP hazards with too little off-chain work to fill).
// Fix: run TWO independent copies (A/B) of the recurrence in different
// registers in the same wave. Both are seeded wave-wide (each computes all
// 8 elements correctly); as independent SSA chains they interleave so B's
// issue fills A's trans stalls. x-buffers + xb projection are shared
// (identical per-lane data). Output: lanes<32 from A, lanes>=32 from B
// (also keeps B live); opaque asm on B's seeds defeats CSE.
//
// Lanes (q=tid&7): l0:i0 l1:i1 l2:f0 l3:f1 l4:o1 l5:o0 l6:g1 l7:g0
// mirror pairs (0,7)(1,6)(2,5)(3,4) = i<->g, f<->o.
// col(l) = (q&1)^((q>>2)&1): l0:0 l1:1 l2:0 l3:1 l4:1 l5:0 l6:1 l7:0.

#define LOG2E 1.4426950408889634f

template <int CTRL>
__device__ __forceinline__ float qdpp(float v) {
    int i = __builtin_bit_cast(int, v);
    i = __builtin_amdgcn_update_dpp(0, i, CTRL, 0xF, 0xF, true);
    return __builtin_bit_cast(float, i);
}
// masked merge DPP: lanes outside row/bank mask keep `old`
template <int CTRL, int BANK>
__device__ __forceinline__ float mdpp(float old, float v) {
    int i = __builtin_amdgcn_update_dpp(__builtin_bit_cast(int, old),
                                        __builtin_bit_cast(int, v),
                                        CTRL, 0xF, BANK, false);
    return __builtin_bit_cast(float, i);
}
#define DPP_MIRROR8 0x141  // row_half_mirror: lane i <-> 7-i
#define DPP_SWAP2   0x4E   // quad_perm(2,3,0,1)
#define DPP_COLSWP  0xB1   // quad_perm(1,0,3,2): adjacent-lane (other col)
#define DPP_ZB_OWN0 0xEE   // quad_perm(2,3,2,3)  (quad0: sigma_o own-col, from mv)
#define DPP_ZB_OWN1 0x44   // quad_perm(0,1,0,1)  (quad1, from n)

__global__ __launch_bounds__(64, 1) void lstm_dual_kernel(
    const float* __restrict__ x,
    const float* __restrict__ h0,
    const float* __restrict__ c0,
    const float* __restrict__ w_ih,
    const float* __restrict__ w_hh,
    const float* __restrict__ b_ih,
    const float* __restrict__ b_hh,
    float* __restrict__ out,
    int B, int T)
{
    const int tid = blockIdx.x * blockDim.x + threadIdx.x;
    const int e = tid >> 3;
    const int q = tid & 7;
    if (e >= B) return;

    const int r = (q < 4) ? q : 11 - q;   // gate row (i0,i1,f0,f1,g0,g1,o0,o1)
    const bool isTanh = (q >= 6);
    const bool sel45  = (q == 4) || (q == 5);
    const bool selMid = (q >= 2) && (q <= 5);
    const int col = (q & 1) ^ ((q >> 2) & 1);

    const float a = isTanh ? (2.0f * LOG2E) : (-LOG2E);
    const float m = isTanh ? (-4.0f * LOG2E) : 1.0f;
    const float d = isTanh ? (2.0f * LOG2E) : 0.0f;

    const float wx0 = w_ih[2 * r] * a, wx1 = w_ih[2 * r + 1] * a;
    const float bias = (b_ih[r] + b_hh[r]) * a;
    const float AwhOwn = w_hh[2 * r + col] * a;
    const float AwhOth = w_hh[2 * r + (1 - col)] * a;
    const float Awh2Own = -2.0f * AwhOwn;
    const float Awh2Oth = -2.0f * AwhOth;

    // Stream A state (valid in ALL lanes; B is an independent copy).
    float r2A = fmaf(-0.5f, h0[2 * e + col], 0.5f);
    float csA = c0[2 * e + col] * (2.0f * LOG2E);
    float V2OwnA = Awh2Own;
    float V2OthA = Awh2Oth;
    float hwA = 0.0f;

    float r2B = r2A, csB = csA, V2OwnB = V2OwnA, V2OthB = V2OthA, hwB = 0.0f;
    // opaque: compiler must not prove B == A (would CSE the whole stream)
    asm volatile("" : "+v"(r2B), "+v"(csB), "+v"(V2OwnB), "+v"(V2OthB));

    const int NI = T >> 1;
    const float4* __restrict__ xp =
        reinterpret_cast<const float4*>(x) + (size_t)e * NI;

    // One step of BOTH streams, manually interleaved. (x0n,x1n) = NEXT
    // step's x pair, folded off-chain into hw; xb shared between streams.
    auto step2 = [&](float x0n, float x1n) {
        float r2oA = qdpp<DPP_COLSWP>(r2A);
        float r2oB = qdpp<DPP_COLSWP>(r2B);
        float gA = fmaf(V2OwnA, r2A, hwA);
        float gB = fmaf(V2OwnB, r2B, hwB);
        gA = fmaf(V2OthA, r2oA, gA);
        gB = fmaf(V2OthB, r2oB, gB);
        float EgA = __builtin_amdgcn_exp2f(gA);
        float EgB = __builtin_amdgcn_exp2f(gB);
        float xb = fmaf(wx1, x1n, fmaf(wx0, x0n, bias));   // shared, off-chain
        float nA = fmaf(m, __builtin_amdgcn_rcpf(1.0f + EgA), d);
        float nB = fmaf(m, __builtin_amdgcn_rcpf(1.0f + EgB), d);
        float mvA = qdpp<DPP_MIRROR8>(nA);
        float mvB = qdpp<DPP_MIRROR8>(nB);
        float XA = sel45 ? mvA : nA;
        float XB = sel45 ? mvB : nB;
        float YA = selMid ? csA : mvA;
        float YB = selMid ? csB : mvB;
        float pA = XA * YA;
        float pB = XB * YB;
        float psA = qdpp<DPP_SWAP2>(pA);
        float psB = qdpp<DPP_SWAP2>(pB);
        csA = pA + psA;
        csB = pB + psB;
        float EpA = __builtin_amdgcn_exp2f(pA);
        float EpB = __builtin_amdgcn_exp2f(pB);
        float EpsA = qdpp<DPP_SWAP2>(EpA);
        float EpsB = qdpp<DPP_SWAP2>(EpB);
        r2A = __builtin_amdgcn_rcpf(fmaf(EpA, EpsA, 1.0f));
        r2B = __builtin_amdgcn_rcpf(fmaf(EpB, EpsB, 1.0f));
        // off-chain rebuild for next step
        float zbA = mdpp<DPP_ZB_OWN0, 0x5>(mvA, mvA);
        float zbB = mdpp<DPP_ZB_OWN0, 0x5>(mvB, mvB);
        zbA = mdpp<DPP_ZB_OWN1, 0xA>(zbA, nA);
        zbB = mdpp<DPP_ZB_OWN1, 0xA>(zbB, nB);
        float zoA = qdpp<DPP_COLSWP>(zbA);
        float zoB = qdpp<DPP_COLSWP>(zbB);
        V2OwnA = Awh2Own * zbA;
        V2OwnB = Awh2Own * zbB;
        V2OthA = Awh2Oth * zoA;
        V2OthB = Awh2Oth * zoB;
        hwA = fmaf(AwhOth, zoA, fmaf(AwhOwn, zbA, xb));
        hwB = fmaf(AwhOth, zoB, fmaf(AwhOwn, zbB, xb));
    };

    constexpr int BV = 8;              // float4s per buffer = 16 timesteps
    float4 A[BV], Bb[BV];

    auto loadbuf = [&](float4* buf, int batch) {
#pragma unroll
        for (int j = 0; j < BV; ++j) buf[j] = xp[batch * BV + j];
    };
    // consume 16 steps; (nx0,nx1) = x pair of the step FOLLOWING this buffer
    auto consume = [&](const float4* buf, float nx0, float nx1) {
#pragma unroll
        for (int j = 0; j < BV; ++j) {
            step2(buf[j].z, buf[j].w);
            if (j + 1 < BV) step2(buf[j + 1].x, buf[j + 1].y);
            else            step2(nx0, nx1);
        }
    };

    const int nb = NI / BV;
    int bi = 0;
    float tnx0 = 0.0f, tnx1 = 0.0f;    // first x pair of the tail region
    if (nb >= 2) {
        loadbuf(A, 0);
        loadbuf(Bb, 1);
        hwA = AwhOwn + AwhOth + fmaf(wx1, A[0].y, fmaf(wx0, A[0].x, bias));
        hwB = hwA;
        if (nb * BV < NI) { float4 t0 = xp[nb * BV]; tnx0 = t0.x; tnx1 = t0.y; }
        for (bi = 0; bi + 1 < nb; bi += 2) {
            const bool moreA = bi + 2 < nb;
            consume(A, Bb[0].x, Bb[0].y);
            if (moreA) loadbuf(A, bi + 2);
            consume(Bb, moreA ? A[0].x : tnx0, moreA ? A[0].y : tnx1);
            if (bi + 3 < nb) loadbuf(Bb, bi + 3);
        }
        if (bi < nb) { consume(A, tnx0, tnx1); ++bi; }
    } else if (NI > 0) {
        float4 v0 = xp[0];
        hwA = AwhOwn + AwhOth + fmaf(wx1, v0.y, fmaf(wx0, v0.x, bias));
        hwB = hwA;
    }
    for (int i = bi * BV; i < NI; ++i) {   // tail (empty for T=2048)
        float4 v = xp[i];
        step2(v.z, v.w);
        if (i + 1 < NI) { float4 w2 = xp[i + 1]; step2(w2.x, w2.y); }
        else            step2(0.0f, 0.0f);
    }

    // lanes < 32 report stream A, lanes >= 32 stream B (identical values;
    // the select keeps both streams live). cs = 2L*c -> c = cs * ln2/2.
    float csF = (threadIdx.x & 32) ? csB : csA;
    if (q < 2) out[2 * e + q] = csF * (0.5f / LOG2E);
}

extern "C" void kernel_launch(void* const* d_in, const int* in_sizes, int n_in,
                              void* d_out, int out_size, void* d_ws, size_t ws_size,
                              hipStream_t stream) {
    const float* x    = (const float*)d_in[0];
    const float* h0   = (const float*)d_in[1];
    const float* c0   = (const float*)d_in[2];
    const float* w_ih = (const float*)d_in[3];
    const float* w_hh = (const float*)d_in[4];
    const float* b_ih = (const float*)d_in[5];
    const float* b_hh = (const float*)d_in[6];
    float* out = (float*)d_out;

    const int B = in_sizes[1] / 2;           // h0 is (B, H=2)
    const int T = in_sizes[0] / (B * 2);     // x is (B, T, D=2)

    const int threads = B * 8;               // 8 lanes per element
    dim3 block(64);
    dim3 grid((threads + 63) / 64);
    hipLaunchKernelGGL(lstm_dual_kernel, grid, block, 0, stream,
                       x, h0, c0, w_ih, w_hh, b_ih, b_hh, out, B, T);
}

// Round 6
// 390.229 us; speedup vs baseline: 1.0145x; 1.0145x over previous
//
#include <hip/hip_runtime.h>

// LSTM scan, B=8192 chains, T=2048 steps, D=H=2. 8 lanes/element.
// Round 13: occupancy-doubling probe, de-risked. Rounds 11/12 (identical
// kernel, divergent `if(lane>=32) return;` at entry) failed twice at the
// container level; this round reaches the SAME hardware condition with no
// divergence at all: blockDim=32 -> hardware launches one wave64 per
// block with lanes 32-63 inactive from dispatch. grid = B/4 = 2048 blocks
// = 2 waves/SIMD (vs 1 for the R9 baseline's exact-fit 1024 waves).
// R10 fit: wall 203cyc/step = busy ~122 (4 wave64 trans @~16cyc dominate)
// + stall ~81 (chain latency one wave can't fill). A second wave/SIMD
// fills the stall IF the issue pass skips the all-inactive upper half.
// H1 (skip): ~100-135us. H2 (trans no-skip): neutral. H3 (no skip):
// ~230-265us regression -> revert to R9 + instruction trims.
// Step math identical to round 9 (r2-carry + de-chained rebuild);
// arithmetic bit-identical => absmax must stay 0.001953125.
//
// Lanes (q=tid&7): l0:i0 l1:i1 l2:f0 l3:f1 l4:o1 l5:o0 l6:g1 l7:g0
// mirror pairs (0,7)(1,6)(2,5)(3,4) = i<->g, f<->o.
// col(l) = (q&1)^((q>>2)&1): l0:0 l1:1 l2:0 l3:1 l4:1 l5:0 l6:1 l7:0.

#define LOG2E 1.4426950408889634f

template <int CTRL>
__device__ __forceinline__ float qdpp(float v) {
    int i = __builtin_bit_cast(int, v);
    i = __builtin_amdgcn_update_dpp(0, i, CTRL, 0xF, 0xF, true);
    return __builtin_bit_cast(float, i);
}
// masked merge DPP: lanes outside row/bank mask keep `old`
template <int CTRL, int BANK>
__device__ __forceinline__ float mdpp(float old, float v) {
    int i = __builtin_amdgcn_update_dpp(__builtin_bit_cast(int, old),
                                        __builtin_bit_cast(int, v),
                                        CTRL, 0xF, BANK, false);
    return __builtin_bit_cast(float, i);
}
#define DPP_MIRROR8 0x141  // row_half_mirror: lane i <-> 7-i
#define DPP_SWAP2   0x4E   // quad_perm(2,3,0,1)
#define DPP_COLSWP  0xB1   // quad_perm(1,0,3,2): adjacent-lane (other col)
#define DPP_ZB_OWN0 0xEE   // quad_perm(2,3,2,3)  (quad0: sigma_o own-col, from mv)
#define DPP_ZB_OWN1 0x44   // quad_perm(0,1,0,1)  (quad1, from n)

__global__ __launch_bounds__(32, 2) void lstm_w32_kernel(
    const float* __restrict__ x,
    const float* __restrict__ h0,
    const float* __restrict__ c0,
    const float* __restrict__ w_ih,
    const float* __restrict__ w_hh,
    const float* __restrict__ b_ih,
    const float* __restrict__ b_hh,
    float* __restrict__ out,
    int B, int T)
{
    const int lane = (int)threadIdx.x;                 // 0..31
    const int e = (int)blockIdx.x * 4 + (lane >> 3);   // 4 elements/block
    const int q = lane & 7;
    if (e >= B) return;

    const int r = (q < 4) ? q : 11 - q;   // gate row (i0,i1,f0,f1,g0,g1,o0,o1)
    const bool isTanh = (q >= 6);
    const bool sel45  = (q == 4) || (q == 5);
    const bool selMid = (q >= 2) && (q <= 5);
    const int col = (q & 1) ^ ((q >> 2) & 1);

    // exp2 arg scale: sigma lanes -log2e, tanh lanes +2*log2e (prefolded).
    // nonlin: n = m*rcp(1+exp2(garg)) + d ; tanh lanes emit 2L*tanh(g).
    const float a = isTanh ? (2.0f * LOG2E) : (-LOG2E);
    const float m = isTanh ? (-4.0f * LOG2E) : 1.0f;
    const float d = isTanh ? (2.0f * LOG2E) : 0.0f;

    const float wx0 = w_ih[2 * r] * a, wx1 = w_ih[2 * r + 1] * a;
    const float bias = (b_ih[r] + b_hh[r]) * a;
    const float AwhOwn = w_hh[2 * r + col] * a;
    const float AwhOth = w_hh[2 * r + (1 - col)] * a;
    const float Awh2Own = -2.0f * AwhOwn;   // r2-form gate coefficients
    const float Awh2Oth = -2.0f * AwhOth;

    // Loop state:
    //   r2 = (1 - tanh(c))/2 own col; seeded with (1-h0)/2 + sigma_o=1 so
    //        step 1 computes g = a*(wx.x + b + wh.h0) exactly.
    //   cs = c scaled by 2*log2e.
    //   V2Own/V2Oth = -2*a*wh*sigma_o
    //   hw = a*(whOwn*sigma_oOwn + whOth*sigma_oOth) + xb(this step)
    float r2 = fmaf(-0.5f, h0[2 * e + col], 0.5f);
    float cs = c0[2 * e + col] * (2.0f * LOG2E);
    float V2Own = Awh2Own;
    float V2Oth = Awh2Oth;
    float hw = 0.0f;   // seeded after first x load

    const int NI = T >> 1;
    const float4* __restrict__ xp =
        reinterpret_cast<const float4*>(x) + (size_t)e * (size_t)NI;

    // step consumes hw (already contains this step's xb); (x0n,x1n) is the
    // NEXT step's x pair, folded into the rebuilt hw off-chain.
    auto step = [&](float x0n, float x1n) {
        // ---- chain: gate from carried (r2, V2, hw) ----
        float r2o = qdpp<DPP_COLSWP>(r2);            // other col (|| inner fma)
        float g   = fmaf(V2Oth, r2o, fmaf(V2Own, r2, hw));
        float n   = fmaf(m, __builtin_amdgcn_rcpf(1.0f + __builtin_amdgcn_exp2f(g)), d);
        float mv  = qdpp<DPP_MIRROR8>(n);
        float X = sel45 ? mv : n;                    // sigma_i|sigma_f|t'g side
        float Y = selMid ? cs : mv;                  // c' | partner nonlin
        float p = X * Y;
        // c update (off main chain; needed next step + epilogue)
        float ps = qdpp<DPP_SWAP2>(p);
        cs = p + ps;
        // r2 via exp2-product: exp2(cs) = exp2(p)*swap(exp2(p))
        float Ep  = __builtin_amdgcn_exp2f(p);
        float Eps = qdpp<DPP_SWAP2>(Ep);
        r2 = __builtin_amdgcn_rcpf(fmaf(Ep, Eps, 1.0f));
        // ---- off-chain rebuild for next step ----
        float xb = fmaf(wx1, x1n, fmaf(wx0, x0n, bias));   // pure-x, hoistable
        float zbOwn = mdpp<DPP_ZB_OWN0, 0x5>(mv, mv);      // sigma_o own-col
        zbOwn = mdpp<DPP_ZB_OWN1, 0xA>(zbOwn, n);
        float zbOth = qdpp<DPP_COLSWP>(zbOwn);             // other-col = colswap
        V2Own = Awh2Own * zbOwn;
        V2Oth = Awh2Oth * zbOth;
        hw = fmaf(AwhOth, zbOth, fmaf(AwhOwn, zbOwn, xb));
    };

    constexpr int BV = 8;              // float4s per buffer = 16 timesteps
    float4 A[BV], Bb[BV];

    auto loadbuf = [&](float4* buf, int batch) {
#pragma unroll
        for (int j = 0; j < BV; ++j) buf[j] = xp[batch * BV + j];
    };
    // consume 16 steps; (nx0,nx1) = x pair of the step FOLLOWING this buffer
    auto consume = [&](const float4* buf, float nx0, float nx1) {
#pragma unroll
        for (int j = 0; j < BV; ++j) {
            step(buf[j].z, buf[j].w);
            if (j + 1 < BV) step(buf[j + 1].x, buf[j + 1].y);
            else            step(nx0, nx1);
        }
    };

    const int nb = NI / BV;
    int bi = 0;
    float tnx0 = 0.0f, tnx1 = 0.0f;    // first x pair of the tail region
    if (nb >= 2) {
        loadbuf(A, 0);
        loadbuf(Bb, 1);
        hw = AwhOwn + AwhOth + fmaf(wx1, A[0].y, fmaf(wx0, A[0].x, bias));
        if (nb * BV < NI) { float4 t0 = xp[nb * BV]; tnx0 = t0.x; tnx1 = t0.y; }
        for (bi = 0; bi + 1 < nb; bi += 2) {
            const bool moreA = bi + 2 < nb;
            consume(A, Bb[0].x, Bb[0].y);
            if (moreA) loadbuf(A, bi + 2);
            consume(Bb, moreA ? A[0].x : tnx0, moreA ? A[0].y : tnx1);
            if (bi + 3 < nb) loadbuf(Bb, bi + 3);
        }
        if (bi < nb) { consume(A, tnx0, tnx1); ++bi; }
    } else if (NI > 0) {
        float4 v0 = xp[0];
        hw = AwhOwn + AwhOth + fmaf(wx1, v0.y, fmaf(wx0, v0.x, bias));
    }
    for (int i = bi * BV; i < NI; ++i) {   // tail (empty for T=2048)
        float4 v = xp[i];
        step(v.z, v.w);
        if (i + 1 < NI) { float4 w2 = xp[i + 1]; step(w2.x, w2.y); }
        else            step(0.0f, 0.0f);
    }

    // cs = 2L*c -> c = cs * ln2/2
    if (q < 2) out[2 * e + q] = cs * (0.5f / LOG2E);
}

extern "C" void kernel_launch(void* const* d_in, const int* in_sizes, int n_in,
                              void* d_out, int out_size, void* d_ws, size_t ws_size,
                              hipStream_t stream) {
    const float* x    = (const float*)d_in[0];
    const float* h0   = (const float*)d_in[1];
    const float* c0   = (const float*)d_in[2];
    const float* w_ih = (const float*)d_in[3];
    const float* w_hh = (const float*)d_in[4];
    const float* b_ih = (const float*)d_in[5];
    const float* b_hh = (const float*)d_in[6];
    float* out = (float*)d_out;

    const int B = in_sizes[1] / 2;           // h0 is (B, H=2)
    const int T = in_sizes[0] / (B * 2);     // x is (B, T, D=2)

    // 4 elements per 32-thread block: one half-populated wave64 per block,
    // lanes 32-63 inactive from dispatch -> 2 waves/SIMD at grid B/4.
    dim3 block(32);
    dim3 grid((B + 3) / 4);
    hipLaunchKernelGGL(lstm_w32_kernel, grid, block, 0, stream,
                       x, h0, c0, w_ih, w_hh, b_ih, b_hh, out, B, T);
}

// Round 7
// 311.427 us; speedup vs baseline: 1.2712x; 1.2530x over previous
//
#include <hip/hip_runtime.h>

// LSTM scan, B=8192 chains, T=2048 steps, D=H=2. 8 lanes/element.
// Round 14: chain-glue trim. R13 probe proved issue cost is
// EXEC-independent (half-wave = full-wave busy) -> occupancy/replication
// paths closed; R9 wall 203cyc/step = CHAIN LATENCY (4 serial trans +
// glue). This round shortens the rcp->exp2 glue from
// [affine-fma -> mirror -> 2 cndmask -> mul] (~24cyc) to
// [maskedDPP/mirror -> 2 parallel muls -> fma] (~18cyc):
//   r    = rcp(1+exp2(g))            (no affine; all lanes)
//   rm   = mirror8(r); rsel = mdpp<MIRROR8,0xA>(r,r)  (0-3:r, 4-7:rm)
//   q    = r*rm;  w = rsel*K;  p = fma(F, q, w)
//   K    = selMid ? cs : 2L   (rebuilt OFF-chain each step)
//   F    = selMid ? 0 : -4L   (per-lane const)
// Lane-verified: l0,1: p=sigma_i*(2L-4L*r_g)  l2,3: p=sigma_f*cs
// l4,5: p=sigma_f*cs (via rm)  l6,7: p=sigma_i*(2L-4L*r_g) (mirrored).
// zb rebuild sourced from r/rm (sigma_o lanes never had the affine).
//
// Lanes (q=tid&7): l0:i0 l1:i1 l2:f0 l3:f1 l4:o1 l5:o0 l6:g1 l7:g0
// mirror pairs (0,7)(1,6)(2,5)(3,4) = i<->g, f<->o.
// col(l) = (q&1)^((q>>2)&1): l0:0 l1:1 l2:0 l3:1 l4:1 l5:0 l6:1 l7:0.

#define LOG2E 1.4426950408889634f

template <int CTRL>
__device__ __forceinline__ float qdpp(float v) {
    int i = __builtin_bit_cast(int, v);
    i = __builtin_amdgcn_update_dpp(0, i, CTRL, 0xF, 0xF, true);
    return __builtin_bit_cast(float, i);
}
// masked merge DPP: lanes outside row/bank mask keep `old`
template <int CTRL, int BANK>
__device__ __forceinline__ float mdpp(float old, float v) {
    int i = __builtin_amdgcn_update_dpp(__builtin_bit_cast(int, old),
                                        __builtin_bit_cast(int, v),
                                        CTRL, 0xF, BANK, false);
    return __builtin_bit_cast(float, i);
}
#define DPP_MIRROR8 0x141  // row_half_mirror: lane i <-> 7-i
#define DPP_SWAP2   0x4E   // quad_perm(2,3,0,1)
#define DPP_COLSWP  0xB1   // quad_perm(1,0,3,2): adjacent-lane (other col)
#define DPP_ZB_OWN0 0xEE   // quad_perm(2,3,2,3)  (quad0: sigma_o own-col, from rm)
#define DPP_ZB_OWN1 0x44   // quad_perm(0,1,0,1)  (quad1, from r)

__global__ __launch_bounds__(64, 1) void lstm_qw_kernel(
    const float* __restrict__ x,
    const float* __restrict__ h0,
    const float* __restrict__ c0,
    const float* __restrict__ w_ih,
    const float* __restrict__ w_hh,
    const float* __restrict__ b_ih,
    const float* __restrict__ b_hh,
    float* __restrict__ out,
    int B, int T)
{
    const int tid = blockIdx.x * blockDim.x + threadIdx.x;
    const int e = tid >> 3;
    const int q = tid & 7;
    if (e >= B) return;

    const int r_ = (q < 4) ? q : 11 - q;  // gate row (i0,i1,f0,f1,g0,g1,o0,o1)
    const bool isTanh = (q >= 6);
    const bool selMid = (q >= 2) && (q <= 5);
    const int col = (q & 1) ^ ((q >> 2) & 1);

    // exp2 arg scale: sigma lanes -log2e, tanh lanes +2*log2e (prefolded).
    const float a = isTanh ? (2.0f * LOG2E) : (-LOG2E);
    // p-combine constant: F = -4L on i/g lanes, 0 on f/o lanes.
    const float F = selMid ? 0.0f : (-4.0f * LOG2E);

    const float wx0 = w_ih[2 * r_] * a, wx1 = w_ih[2 * r_ + 1] * a;
    const float bias = (b_ih[r_] + b_hh[r_]) * a;
    const float AwhOwn = w_hh[2 * r_ + col] * a;
    const float AwhOth = w_hh[2 * r_ + (1 - col)] * a;
    const float Awh2Own = -2.0f * AwhOwn;   // r2-form gate coefficients
    const float Awh2Oth = -2.0f * AwhOth;

    // Loop state:
    //   r2 = (1 - tanh(c))/2 own col; seed (1-h0)/2 with sigma_o=1.
    //   cs = c scaled by 2*log2e.
    //   V2Own/V2Oth = -2*a*wh*sigma_o
    //   hw = a*(whOwn*so_own + whOth*so_oth) + xb(this step)
    //   K  = selMid ? cs : 2L  (off-chain per step)
    float r2 = fmaf(-0.5f, h0[2 * e + col], 0.5f);
    float cs = c0[2 * e + col] * (2.0f * LOG2E);
    float V2Own = Awh2Own;
    float V2Oth = Awh2Oth;
    float hw = 0.0f;   // seeded after first x load
    float K  = selMid ? cs : (2.0f * LOG2E);

    const int NI = T >> 1;
    const float4* __restrict__ xp =
        reinterpret_cast<const float4*>(x) + (size_t)e * NI;

    // step consumes hw (already contains this step's xb); (x0n,x1n) is the
    // NEXT step's x pair, folded into the rebuilt hw off-chain.
    auto step = [&](float x0n, float x1n) {
        // ---- chain: gate from carried (r2, V2, hw) ----
        float r2o = qdpp<DPP_COLSWP>(r2);            // other col (|| inner fma)
        float g   = fmaf(V2Oth, r2o, fmaf(V2Own, r2, hw));
        float r   = __builtin_amdgcn_rcpf(1.0f + __builtin_amdgcn_exp2f(g));
        // p via q/w scheme: chain r -> {rm,rsel} -> {q,w} -> fma -> exp2
        float rm   = qdpp<DPP_MIRROR8>(r);           // full mirror
        float rsel = mdpp<DPP_MIRROR8, 0xA>(r, r);   // 0-3: r, 4-7: rm
        float qq   = r * rm;
        float w    = rsel * K;                       // K off-chain (prev cs)
        float p    = fmaf(F, qq, w);
        // c update (off main chain; needed next step + epilogue)
        float ps = qdpp<DPP_SWAP2>(p);
        cs = p + ps;
        // r2 via exp2-product: exp2(cs) = exp2(p)*swap(exp2(p))
        float Ep  = __builtin_amdgcn_exp2f(p);
        float Eps = qdpp<DPP_SWAP2>(Ep);
        r2 = __builtin_amdgcn_rcpf(fmaf(Ep, Eps, 1.0f));
        // ---- off-chain rebuild for next step ----
        K = selMid ? cs : (2.0f * LOG2E);            // refresh K
        float xb = fmaf(wx1, x1n, fmaf(wx0, x0n, bias));   // pure-x
        float zbOwn = mdpp<DPP_ZB_OWN0, 0x5>(rm, rm);      // sigma_o own-col
        zbOwn = mdpp<DPP_ZB_OWN1, 0xA>(zbOwn, r);
        float zbOth = qdpp<DPP_COLSWP>(zbOwn);             // other-col
        V2Own = Awh2Own * zbOwn;
        V2Oth = Awh2Oth * zbOth;
        hw = fmaf(AwhOth, zbOth, fmaf(AwhOwn, zbOwn, xb));
    };

    constexpr int BV = 8;              // float4s per buffer = 16 timesteps
    float4 A[BV], Bb[BV];

    auto loadbuf = [&](float4* buf, int batch) {
#pragma unroll
        for (int j = 0; j < BV; ++j) buf[j] = xp[batch * BV + j];
    };
    // consume 16 steps; (nx0,nx1) = x pair of the step FOLLOWING this buffer
    auto consume = [&](const float4* buf, float nx0, float nx1) {
#pragma unroll
        for (int j = 0; j < BV; ++j) {
            step(buf[j].z, buf[j].w);
            if (j + 1 < BV) step(buf[j + 1].x, buf[j + 1].y);
            else            step(nx0, nx1);
        }
    };

    const int nb = NI / BV;
    int bi = 0;
    float tnx0 = 0.0f, tnx1 = 0.0f;    // first x pair of the tail region
    if (nb >= 2) {
        loadbuf(A, 0);
        loadbuf(Bb, 1);
        hw = AwhOwn + AwhOth + fmaf(wx1, A[0].y, fmaf(wx0, A[0].x, bias));
        if (nb * BV < NI) { float4 t0 = xp[nb * BV]; tnx0 = t0.x; tnx1 = t0.y; }
        for (bi = 0; bi + 1 < nb; bi += 2) {
            const bool moreA = bi + 2 < nb;
            consume(A, Bb[0].x, Bb[0].y);
            if (moreA) loadbuf(A, bi + 2);
            consume(Bb, moreA ? A[0].x : tnx0, moreA ? A[0].y : tnx1);
            if (bi + 3 < nb) loadbuf(Bb, bi + 3);
        }
        if (bi < nb) { consume(A, tnx0, tnx1); ++bi; }
    } else if (NI > 0) {
        float4 v0 = xp[0];
        hw = AwhOwn + AwhOth + fmaf(wx1, v0.y, fmaf(wx0, v0.x, bias));
    }
    for (int i = bi * BV; i < NI; ++i) {   // tail (empty for T=2048)
        float4 v = xp[i];
        step(v.z, v.w);
        if (i + 1 < NI) { float4 w2 = xp[i + 1]; step(w2.x, w2.y); }
        else            step(0.0f, 0.0f);
    }

    // cs = 2L*c -> c = cs * ln2/2
    if (q < 2) out[2 * e + q] = cs * (0.5f / LOG2E);
}

extern "C" void kernel_launch(void* const* d_in, const int* in_sizes, int n_in,
                              void* d_out, int out_size, void* d_ws, size_t ws_size,
                              hipStream_t stream) {
    const float* x    = (const float*)d_in[0];
    const float* h0   = (const float*)d_in[1];
    const float* c0   = (const float*)d_in[2];
    const float* w_ih = (const float*)d_in[3];
    const float* w_hh = (const float*)d_in[4];
    const float* b_ih = (const float*)d_in[5];
    const float* b_hh = (const float*)d_in[6];
    float* out = (float*)d_out;

    const int B = in_sizes[1] / 2;           // h0 is (B, H=2)
    const int T = in_sizes[0] / (B * 2);     // x is (B, T, D=2)

    const int threads = B * 8;               // 8 lanes per element
    dim3 block(64);
    dim3 grid((threads + 63) / 64);
    hipLaunchKernelGGL(lstm_qw_kernel, grid, block, 0, stream,
                       x, h0, c0, w_ih, w_hh, b_ih, b_hh, out, B, T);
}